// Round 14
// baseline (987.584 us; speedup 1.0000x reference)
//
#include <hip/hip_runtime.h>

#define B_ 32
#define N_ 8192
#define G_ 512
#define K_ 32
#define EPSF 1e-5f

typedef __attribute__((ext_vector_type(8))) short bf16x8;
typedef __attribute__((ext_vector_type(4))) float f32x4;
typedef __attribute__((ext_vector_type(2))) unsigned long long u64x2;

static __device__ __forceinline__ short f2bf(float f) {
    unsigned u = __float_as_uint(f);
    u += 0x7fffu + ((u >> 16) & 1u);  // round-to-nearest-even
    return (short)(u >> 16);
}

static __device__ __forceinline__ unsigned long long u64max(unsigned long long a,
                                                            unsigned long long b) {
    return a > b ? a : b;
}
static __device__ __forceinline__ unsigned umin32(unsigned a, unsigned b) {
    return a < b ? a : b;
}

// DPP row_shr:<N> move of a u64, 0-fill (max-neutral for non-negative keys).
template <int CTL>
static __device__ __forceinline__ unsigned long long dpp_shr_u64(unsigned long long k) {
    const int lo = __builtin_amdgcn_mov_dpp((int)(unsigned)k, CTL, 0xf, 0xf, true);
    const int hi = __builtin_amdgcn_mov_dpp((int)(unsigned)(k >> 32), CTL, 0xf, 0xf, true);
    return ((unsigned long long)(unsigned)hi << 32) | (unsigned)lo;
}

// DPP move of a u32 that PRESERVES the old value on unwritten/invalid lanes
// (bound_ctrl=false, old=own value) -> safe for MIN reductions (no 0-fill).
template <int CTL>
static __device__ __forceinline__ unsigned dpp_upd_u32(unsigned v) {
    return (unsigned)__builtin_amdgcn_update_dpp((int)v, (int)v, CTL, 0xf, 0xf, false);
}

// full-wave u32 min ladder -> result broadcast from lane 63
static __device__ __forceinline__ unsigned wave_min_u32(unsigned v) {
    v = umin32(v, dpp_upd_u32<0x111>(v));
    v = umin32(v, dpp_upd_u32<0x112>(v));
    v = umin32(v, dpp_upd_u32<0x114>(v));
    v = umin32(v, dpp_upd_u32<0x118>(v));
    v = umin32(v, dpp_upd_u32<0x142>(v));  // row_bcast15
    v = umin32(v, dpp_upd_u32<0x143>(v));  // row_bcast31
    return (unsigned)__builtin_amdgcn_readlane((int)v, 63);
}

// ---------------------------------------------------------------------------
// Prep: fold BN (inference) into weights/biases once.
// ---------------------------------------------------------------------------
__global__ __launch_bounds__(256) void prep_kernel(
    const float* __restrict__ w0, const float* __restrict__ b0,
    const float* __restrict__ g0, const float* __restrict__ be0,
    const float* __restrict__ m0, const float* __restrict__ v0,
    const float* __restrict__ w1, const float* __restrict__ b1,
    const float* __restrict__ g1, const float* __restrict__ be1,
    const float* __restrict__ m1, const float* __restrict__ v1,
    const float* __restrict__ w2, const float* __restrict__ b2,
    const float* __restrict__ g2, const float* __restrict__ be2,
    const float* __restrict__ m2, const float* __restrict__ v2,
    float* __restrict__ W0b, float* __restrict__ b1b, float* __restrict__ b2b,
    short* __restrict__ W1b, short* __restrict__ W2b) {
    const int t = threadIdx.x;
    if (t < 64) {
        const float sc = g0[t] / sqrtf(v0[t] + EPSF);
        W0b[t * 4 + 0] = w0[t * 3 + 0] * sc;
        W0b[t * 4 + 1] = w0[t * 3 + 1] * sc;
        W0b[t * 4 + 2] = w0[t * 3 + 2] * sc;
        W0b[t * 4 + 3] = (b0[t] - m0[t]) * sc + be0[t];
    }
    if (t < 128) b1b[t] = (b1[t] - m1[t]) * (g1[t] / sqrtf(v1[t] + EPSF)) + be1[t];
    if (t < 256) b2b[t] = (b2[t] - m2[t]) * (g2[t] / sqrtf(v2[t] + EPSF)) + be2[t];
    for (int i = t; i < 128 * 64; i += 256) {
        const int o = i >> 6;
        const float sc = g1[o] / sqrtf(v1[o] + EPSF);
        W1b[i] = f2bf(w1[i] * sc);
    }
    for (int i = t; i < 256 * 128; i += 256) {
        const int o = i >> 7;
        const float sc = g2[o] / sqrtf(v2[o] + EPSF);
        W2b[i] = f2bf(w2[i] * sc);
    }
}

// ---------------------------------------------------------------------------
// Kernel 1: FPS — R5/R11/R13-verbatim (measured best: 455us, VGPR 88).
// ---------------------------------------------------------------------------
__global__ __launch_bounds__(512) void fps_kernel(const float* __restrict__ pts,
                                                  float* __restrict__ centers) {
    __shared__ float4 sxyz[N_];  // 128KB
    __shared__ __align__(16) unsigned long long rowkeys[2][32];

    const int b = blockIdx.x;
    const int t = threadIdx.x;
    const int l = t & 63;
    const int w = t >> 6;
    const float* p = pts + (size_t)b * (N_ * 3);

    float px[16], py[16], pz[16], md[16];
#pragma unroll
    for (int j = 0; j < 16; ++j) {
        const int idx = t + j * 512;
        px[j] = p[3 * idx + 0];
        py[j] = p[3 * idx + 1];
        pz[j] = p[3 * idx + 2];
        sxyz[idx] = make_float4(px[j], py[j], pz[j], 0.0f);
        md[j] = 1e10f;
    }
    __syncthreads();

    if (t == 0) {
        float* c = centers + (size_t)b * (G_ * 3);
        c[0] = px[0]; c[1] = py[0]; c[2] = pz[0];
    }
    const float4 c0 = sxyz[0];
    float lx = c0.x, ly = c0.y, lz = c0.z;
    const int pay0 = 8191 - t;  // idx = t + j*512 -> pay = pay0 - (j<<9)

    for (int g = 1; g < G_; ++g) {
        float m_best = -1.0f;
        int j_best = 0;
#pragma unroll
        for (int j = 0; j < 16; ++j) {
            const float dx = __fsub_rn(px[j], lx);
            const float dy = __fsub_rn(py[j], ly);
            const float dz = __fsub_rn(pz[j], lz);
            const float d = __fadd_rn(__fadd_rn(__fmul_rn(dx, dx), __fmul_rn(dy, dy)),
                                      __fmul_rn(dz, dz));
            const float m = fminf(md[j], d);
            md[j] = m;
            const bool c = m > m_best;  // strict: keeps smallest j on ties
            m_best = c ? m : m_best;
            j_best = c ? j : j_best;
        }
        unsigned long long key =
            ((unsigned long long)__float_as_uint(m_best) << 13) |
            (unsigned long long)(unsigned)(pay0 - (j_best << 9));

        key = u64max(key, dpp_shr_u64<0x111>(key));
        key = u64max(key, dpp_shr_u64<0x112>(key));
        key = u64max(key, dpp_shr_u64<0x114>(key));
        key = u64max(key, dpp_shr_u64<0x118>(key));
        if ((l & 15) == 15) rowkeys[g & 1][w * 4 + (l >> 4)] = key;  // 32 rows
        __syncthreads();

        const u64x2* rk = (const u64x2*)&rowkeys[g & 1][0];
        const u64x2 k2 = rk[l & 15];
        unsigned long long kk = u64max(k2[0], k2[1]);
        kk = u64max(kk, dpp_shr_u64<0x111>(kk));
        kk = u64max(kk, dpp_shr_u64<0x112>(kk));
        kk = u64max(kk, dpp_shr_u64<0x114>(kk));
        kk = u64max(kk, dpp_shr_u64<0x118>(kk));
        const unsigned blo =
            (unsigned)__builtin_amdgcn_readlane((int)(unsigned)kk, 15);
        const int last = 8191 - (int)(blo & 0x1FFFu);

        const float4 cc = sxyz[last];  // broadcast read
        lx = cc.x; ly = cc.y; lz = cc.z;
        if (t == 0) {
            float* c = centers + ((size_t)b * G_ + g) * 3;
            c[0] = lx; c[1] = ly; c[2] = lz;
        }
    }
}

// ---------------------------------------------------------------------------
// Kernel 2: kNN v5 — all-u32 round loop with lazy index resolution.
// Group mins gm0..gm3 and lane-min ld are u32 DIST BITS only (no u64 keys in
// the loop). Per round: u32 dist ladder -> m*; dist-tied lanes (usually 1)
// locate their first matching slot (lowest group, then lowest slot == lowest
// in-lane idx) and form myidx; ballot fast path readlane / rare-tie idx
// ladder (exact). Owner check = (myidx == istar), unique since idx unique.
// Selection order provably == u64-lex (dist, idx) min. Rank-merge unchanged.
// ---------------------------------------------------------------------------
__global__ __launch_bounds__(256) void knn_kernel(const float* __restrict__ pts,
                                                  const float* __restrict__ centers,
                                                  float* __restrict__ neigh) {
    __shared__ unsigned long long wkeys[4][32];
    __shared__ int midx[32];

    const int cid = blockIdx.x;
    const int b = cid >> 9;
    const int t = threadIdx.x;
    const int w = t >> 6;
    const int l = t & 63;
    const float* p = pts + (size_t)b * (N_ * 3);
    const float* c = centers + (size_t)cid * 3;
    const float cx = c[0], cy = c[1], cz = c[2];

    const int iy0 = (w << 11) + l;

    unsigned db[32];
#pragma unroll
    for (int i = 0; i < 32; ++i) {
        const int idx = iy0 + (i << 6);
        const float dx = __fsub_rn(p[3 * idx + 0], cx);
        const float dy = __fsub_rn(p[3 * idx + 1], cy);
        const float dz = __fsub_rn(p[3 * idx + 2], cz);
        const float d = __fadd_rn(__fadd_rn(__fmul_rn(dx, dx), __fmul_rn(dy, dy)),
                                  __fmul_rn(dz, dz));
        db[i] = __float_as_uint(d);
    }

#define GMIN8(G)                                                              \
    umin32(umin32(umin32(db[(G)*8 + 0], db[(G)*8 + 1]),                       \
                  umin32(db[(G)*8 + 2], db[(G)*8 + 3])),                      \
           umin32(umin32(db[(G)*8 + 4], db[(G)*8 + 5]),                       \
                  umin32(db[(G)*8 + 6], db[(G)*8 + 7])))
// first (lowest) slot in group G equal to M -> ILOC (local 0..31 index)
#define FIND_IN_GROUP(G, M, ILOC)                                             \
    {                                                                         \
        ILOC = (G)*8 + 7;                                                     \
        _Pragma("unroll") for (int j = 6; j >= 0; --j) {                      \
            if (db[(G)*8 + j] == (M)) ILOC = (G)*8 + j;                       \
        }                                                                     \
    }
// exclude slot ILOC (runtime) via static-indexed stores
#define EXCL_IN_GROUP(G, ILOC)                                                \
    {                                                                         \
        _Pragma("unroll") for (int j = 0; j < 8; ++j) {                       \
            if ((G)*8 + j == (ILOC)) db[(G)*8 + j] = 0xFFFFFFFFu;             \
        }                                                                     \
    }

    unsigned gm0 = GMIN8(0), gm1 = GMIN8(1), gm2 = GMIN8(2), gm3 = GMIN8(3);
    unsigned ld = umin32(umin32(gm0, gm1), umin32(gm2, gm3));

    for (int r = 0; r < K_; ++r) {
        const unsigned mstar = wave_min_u32(ld);
        const unsigned long long bal = __ballot(ld == mstar);

        // tied lanes resolve their lowest matching in-lane index
        unsigned myidx = 0xFFFFFFFFu;
        int iloc = -1;
        if (ld == mstar) {
            const int grp =
                (gm0 == mstar) ? 0 : ((gm1 == mstar) ? 1 : ((gm2 == mstar) ? 2 : 3));
            switch (grp) {
                case 0: FIND_IN_GROUP(0, mstar, iloc) break;
                case 1: FIND_IN_GROUP(1, mstar, iloc) break;
                case 2: FIND_IN_GROUP(2, mstar, iloc) break;
                default: FIND_IN_GROUP(3, mstar, iloc) break;
            }
            myidx = (unsigned)(iy0 + (iloc << 6));
        }

        unsigned istar;
        if (__popcll(bal) == 1) {
            const int wl = (int)(__ffsll((long long)bal) - 1);
            istar = (unsigned)__builtin_amdgcn_readlane((int)myidx, wl);
        } else {
            // rare multi-tie: exact idx-min ladder among tied lanes
            unsigned il = myidx;  // untied lanes hold ~0
            il = umin32(il, dpp_upd_u32<0x111>(il));
            il = umin32(il, dpp_upd_u32<0x112>(il));
            il = umin32(il, dpp_upd_u32<0x114>(il));
            il = umin32(il, dpp_upd_u32<0x118>(il));
            il = umin32(il, dpp_upd_u32<0x142>(il));
            il = umin32(il, dpp_upd_u32<0x143>(il));
            istar = (unsigned)__builtin_amdgcn_readlane((int)il, 63);
        }

        if (myidx == istar) {  // unique owner (idx unique; untied lanes ~0)
            switch (iloc >> 3) {
                case 0: EXCL_IN_GROUP(0, iloc) gm0 = GMIN8(0); break;
                case 1: EXCL_IN_GROUP(1, iloc) gm1 = GMIN8(1); break;
                case 2: EXCL_IN_GROUP(2, iloc) gm2 = GMIN8(2); break;
                default: EXCL_IN_GROUP(3, iloc) gm3 = GMIN8(3); break;
            }
            ld = umin32(umin32(gm0, gm1), umin32(gm2, gm3));
        }
        if (l == 0)
            wkeys[w][r] =
                ((unsigned long long)mstar << 13) | (unsigned long long)istar;
    }
#undef GMIN8
#undef FIND_IN_GROUP
#undef EXCL_IN_GROUP
    __syncthreads();

    // parallel rank-merge of 4 sorted 32-lists (keys unique -> strict less)
    if (t < 128) {
        const int wv = t >> 5;
        const int pos = t & 31;
        const unsigned long long mykey = wkeys[wv][pos];
        int rank = pos;
#pragma unroll
        for (int d = 1; d < 4; ++d) {
            const int ol = (wv + d) & 3;
            int cnt = 0;
#pragma unroll
            for (int s = 32; s >= 1; s >>= 1) {
                const int n = cnt + s;
                if (n <= 32 && wkeys[ol][n - 1] < mykey) cnt = n;
            }
            rank += cnt;
        }
        if (rank < 32) midx[rank] = (int)(mykey & 0x1FFFull);
    }
    __syncthreads();

    if (t < 32) {
        const int idx = midx[t];
        float* o3 = neigh + (((size_t)cid * K_) + t) * 3;
        o3[0] = __fsub_rn(p[3 * idx + 0], cx);
        o3[1] = __fsub_rn(p[3 * idx + 1], cy);
        o3[2] = __fsub_rn(p[3 * idx + 2], cz);
    }
}

// ---------------------------------------------------------------------------
// Kernel 3: MFMA MLP (unchanged from R4-R13 — proven). 512 thr x 256 pts/blk.
// ---------------------------------------------------------------------------
__global__ __launch_bounds__(512) void mlp_kernel(
    const float* __restrict__ neigh, const float* __restrict__ W0b,
    const float* __restrict__ b1b, const float* __restrict__ b2b,
    const short* __restrict__ W1b, const short* __restrict__ W2b,
    float* __restrict__ out) {
    __shared__ bf16x8 lw1v[1024];
    __shared__ bf16x8 lw2v[4096];
    __shared__ bf16x8 lh2v[8 * 512];
    __shared__ float lw0[256];
    __shared__ float lb1[128];
    __shared__ float lb2[256];
    __shared__ float colmax[256];

    const int t = threadIdx.x;
    const int w = t >> 6;
    const int l = t & 63;
    const int lr = l & 15;
    const int lg = l >> 4;

    {
        char* d1 = (char*)lw1v;
        for (int i = t; i < 1024; i += 512) {
            const int d = i * 16;
            const int src = d ^ ((((unsigned)d >> 7) & 7) << 4);
            *(bf16x8*)(d1 + d) = *(const bf16x8*)((const char*)W1b + src);
        }
        char* d2 = (char*)lw2v;
        for (int i = t; i < 4096; i += 512) {
            const int d = i * 16;
            const int src = d ^ ((((unsigned)d >> 8) & 7) << 4);
            *(bf16x8*)(d2 + d) = *(const bf16x8*)((const char*)W2b + src);
        }
        if (t < 256) lw0[t] = W0b[t];
        if (t < 128) lb1[t] = b1b[t];
        if (t < 256) lb2[t] = b2b[t];
        if (t < 256) colmax[t] = 0.0f;
    }
    __syncthreads();

    const size_t pbase = (size_t)blockIdx.x * 256 + w * 32;
    bf16x8 a1[2][2];
#pragma unroll
    for (int m = 0; m < 2; ++m) {
        const float* pp = neigh + (pbase + m * 16 + lr) * 3;
        const float x0 = pp[0], x1 = pp[1], x2 = pp[2];
#pragma unroll
        for (int s = 0; s < 2; ++s) {
            bf16x8 v;
#pragma unroll
            for (int j = 0; j < 8; ++j) {
                const int c = s * 32 + lg * 8 + j;
                const float4 wv = *(const float4*)&lw0[c * 4];
                float val = fmaf(x2, wv.z, fmaf(x1, wv.y, x0 * wv.x)) + wv.w;
                v[j] = f2bf(fmaxf(val, 0.0f));
            }
            a1[m][s] = v;
        }
    }

    const f32x4 vzero = {0.f, 0.f, 0.f, 0.f};
    f32x4 acc2[2][8];
#pragma unroll
    for (int m = 0; m < 2; ++m)
#pragma unroll
        for (int n = 0; n < 8; ++n) acc2[m][n] = vzero;

    const char* w1p = (const char*)lw1v;
#pragma unroll
    for (int s = 0; s < 2; ++s) {
#pragma unroll
        for (int n = 0; n < 8; ++n) {
            const int o = n * 16 + lr;
            int byte = o * 128 + s * 64 + lg * 16;
            byte ^= ((o & 7) << 4);
            const bf16x8 bfr = *(const bf16x8*)(w1p + byte);
            acc2[0][n] = __builtin_amdgcn_mfma_f32_16x16x32_bf16(a1[0][s], bfr, acc2[0][n], 0, 0, 0);
            acc2[1][n] = __builtin_amdgcn_mfma_f32_16x16x32_bf16(a1[1][s], bfr, acc2[1][n], 0, 0, 0);
        }
    }

    char* myh2 = (char*)(lh2v + w * 512);
#pragma unroll
    for (int m = 0; m < 2; ++m)
#pragma unroll
        for (int n = 0; n < 8; ++n) {
            const int o = n * 16 + lr;
            const float bb = lb1[o];
#pragma unroll
            for (int q = 0; q < 4; ++q) {
                const int row = m * 16 + lg * 4 + q;
                int byte = row * 256 + o * 2;
                byte ^= ((row & 7) << 4);
                *(short*)(myh2 + byte) = f2bf(fmaxf(acc2[m][n][q] + bb, 0.0f));
            }
        }

    f32x4 acc3[2][16];
#pragma unroll
    for (int m = 0; m < 2; ++m)
#pragma unroll
        for (int n = 0; n < 16; ++n) acc3[m][n] = vzero;

    const char* w2p = (const char*)lw2v;
#pragma unroll
    for (int s = 0; s < 4; ++s) {
        bf16x8 a[2];
#pragma unroll
        for (int m = 0; m < 2; ++m) {
            const int row = m * 16 + lr;
            int byte = row * 256 + s * 64 + lg * 16;
            byte ^= ((row & 7) << 4);
            a[m] = *(const bf16x8*)(myh2 + byte);
        }
#pragma unroll
        for (int n = 0; n < 16; ++n) {
            const int o = n * 16 + lr;
            int byte = o * 256 + s * 64 + lg * 16;
            byte ^= ((o & 7) << 4);
            const bf16x8 bfr = *(const bf16x8*)(w2p + byte);
            acc3[0][n] = __builtin_amdgcn_mfma_f32_16x16x32_bf16(a[0], bfr, acc3[0][n], 0, 0, 0);
            acc3[1][n] = __builtin_amdgcn_mfma_f32_16x16x32_bf16(a[1], bfr, acc3[1][n], 0, 0, 0);
        }
    }

#pragma unroll
    for (int n = 0; n < 16; ++n) {
        const int o = n * 16 + lr;
        const float bb = lb2[o];
        float mx = 0.0f;
#pragma unroll
        for (int m = 0; m < 2; ++m)
#pragma unroll
            for (int q = 0; q < 4; ++q) mx = fmaxf(mx, acc3[m][n][q] + bb);
        mx = fmaxf(mx, 0.0f);
        mx = fmaxf(mx, __shfl_xor(mx, 16, 64));
        mx = fmaxf(mx, __shfl_xor(mx, 32, 64));
        if (lg == 0) atomicMax((unsigned int*)&colmax[o], __float_as_uint(mx));
    }
    __syncthreads();
    if (t < 256) {
        const int b = (int)(blockIdx.x >> 6);
        atomicMax((unsigned int*)out + b * 256 + t, __float_as_uint(colmax[t]));
    }
}

// ---------------------------------------------------------------------------
extern "C" void kernel_launch(void* const* d_in, const int* in_sizes, int n_in,
                              void* d_out, int out_size, void* d_ws, size_t ws_size,
                              hipStream_t stream) {
    const float* pts = (const float*)d_in[0];
    const float* w0 = (const float*)d_in[1];
    const float* b0 = (const float*)d_in[2];
    const float* g0 = (const float*)d_in[3];
    const float* be0 = (const float*)d_in[4];
    const float* m0 = (const float*)d_in[5];
    const float* v0 = (const float*)d_in[6];
    const float* w1 = (const float*)d_in[7];
    const float* b1 = (const float*)d_in[8];
    const float* g1 = (const float*)d_in[9];
    const float* be1 = (const float*)d_in[10];
    const float* m1 = (const float*)d_in[11];
    const float* v1 = (const float*)d_in[12];
    const float* w2 = (const float*)d_in[13];
    const float* b2 = (const float*)d_in[14];
    const float* g2 = (const float*)d_in[15];
    const float* be2 = (const float*)d_in[16];
    const float* m2 = (const float*)d_in[17];
    const float* v2 = (const float*)d_in[18];

    char* ws = (char*)d_ws;
    float* centers = (float*)ws;                        // 192KB @ 0
    float* neigh = (float*)(ws + (size_t)262144);       // 6.29MB
    char* wb = ws + (size_t)6553600;                    // weights region
    float* W0b = (float*)(wb + 0);                      // 1KB
    float* b1b = (float*)(wb + 1024);                   // 512B
    float* b2b = (float*)(wb + 1536);                   // 1KB
    short* W1b = (short*)(wb + 2560);                   // 16KB
    short* W2b = (short*)(wb + 2560 + 16384);           // 64KB

    hipMemsetAsync(d_out, 0, (size_t)out_size * sizeof(float), stream);
    prep_kernel<<<1, 256, 0, stream>>>(w0, b0, g0, be0, m0, v0,
                                       w1, b1, g1, be1, m1, v1,
                                       w2, b2, g2, be2, m2, v2,
                                       W0b, b1b, b2b, W1b, W2b);
    fps_kernel<<<B_, 512, 0, stream>>>(pts, centers);
    knn_kernel<<<B_ * G_, 256, 0, stream>>>(pts, centers, neigh);
    mlp_kernel<<<(B_ * G_ * K_) / 256, 512, 0, stream>>>(
        neigh, W0b, b1b, b2b, W1b, W2b, (float*)d_out);
}

// Round 15
// 856.479 us; speedup vs baseline: 1.1531x; 1.1531x over previous
//
#include <hip/hip_runtime.h>

#define B_ 32
#define N_ 8192
#define G_ 512
#define K_ 32
#define EPSF 1e-5f

typedef __attribute__((ext_vector_type(8))) short bf16x8;
typedef __attribute__((ext_vector_type(4))) float f32x4;
typedef __attribute__((ext_vector_type(2))) unsigned long long u64x2;

static __device__ __forceinline__ short f2bf(float f) {
    unsigned u = __float_as_uint(f);
    u += 0x7fffu + ((u >> 16) & 1u);  // round-to-nearest-even
    return (short)(u >> 16);
}

static __device__ __forceinline__ unsigned long long u64max(unsigned long long a,
                                                            unsigned long long b) {
    return a > b ? a : b;
}
static __device__ __forceinline__ unsigned long long u64min(unsigned long long a,
                                                            unsigned long long b) {
    return a < b ? a : b;
}
static __device__ __forceinline__ unsigned umin32(unsigned a, unsigned b) {
    return a < b ? a : b;
}

// DPP row_shr:<N> move of a u64, 0-fill (max-neutral for non-negative keys).
template <int CTL>
static __device__ __forceinline__ unsigned long long dpp_shr_u64(unsigned long long k) {
    const int lo = __builtin_amdgcn_mov_dpp((int)(unsigned)k, CTL, 0xf, 0xf, true);
    const int hi = __builtin_amdgcn_mov_dpp((int)(unsigned)(k >> 32), CTL, 0xf, 0xf, true);
    return ((unsigned long long)(unsigned)hi << 32) | (unsigned)lo;
}

// DPP move of a u32 that PRESERVES the old value on unwritten/invalid lanes
// (bound_ctrl=false, old=own value) -> safe for MIN reductions (no 0-fill).
template <int CTL>
static __device__ __forceinline__ unsigned dpp_upd_u32(unsigned v) {
    return (unsigned)__builtin_amdgcn_update_dpp((int)v, (int)v, CTL, 0xf, 0xf, false);
}

// full-wave u32 min ladder -> result broadcast from lane 63
static __device__ __forceinline__ unsigned wave_min_u32(unsigned v) {
    v = umin32(v, dpp_upd_u32<0x111>(v));
    v = umin32(v, dpp_upd_u32<0x112>(v));
    v = umin32(v, dpp_upd_u32<0x114>(v));
    v = umin32(v, dpp_upd_u32<0x118>(v));
    v = umin32(v, dpp_upd_u32<0x142>(v));  // row_bcast15
    v = umin32(v, dpp_upd_u32<0x143>(v));  // row_bcast31
    return (unsigned)__builtin_amdgcn_readlane((int)v, 63);
}

// ---------------------------------------------------------------------------
// Prep: fold BN into weights/biases once. Parallelized across 17 blocks
// (block 0: small vectors; all blocks stripe W1b/W2b — disjoint writes).
// ---------------------------------------------------------------------------
__global__ __launch_bounds__(256) void prep_kernel(
    const float* __restrict__ w0, const float* __restrict__ b0,
    const float* __restrict__ g0, const float* __restrict__ be0,
    const float* __restrict__ m0, const float* __restrict__ v0,
    const float* __restrict__ w1, const float* __restrict__ b1,
    const float* __restrict__ g1, const float* __restrict__ be1,
    const float* __restrict__ m1, const float* __restrict__ v1,
    const float* __restrict__ w2, const float* __restrict__ b2,
    const float* __restrict__ g2, const float* __restrict__ be2,
    const float* __restrict__ m2, const float* __restrict__ v2,
    float* __restrict__ W0b, float* __restrict__ b1b, float* __restrict__ b2b,
    short* __restrict__ W1b, short* __restrict__ W2b) {
    const int t = threadIdx.x;
    const int gid = blockIdx.x * 256 + t;
    const int stride = gridDim.x * 256;
    if (blockIdx.x == 0) {
        if (t < 64) {
            const float sc = g0[t] / sqrtf(v0[t] + EPSF);
            W0b[t * 4 + 0] = w0[t * 3 + 0] * sc;
            W0b[t * 4 + 1] = w0[t * 3 + 1] * sc;
            W0b[t * 4 + 2] = w0[t * 3 + 2] * sc;
            W0b[t * 4 + 3] = (b0[t] - m0[t]) * sc + be0[t];
        }
        if (t < 128) b1b[t] = (b1[t] - m1[t]) * (g1[t] / sqrtf(v1[t] + EPSF)) + be1[t];
        if (t < 256) b2b[t] = (b2[t] - m2[t]) * (g2[t] / sqrtf(v2[t] + EPSF)) + be2[t];
    }
    for (int i = gid; i < 128 * 64; i += stride) {
        const int o = i >> 6;
        const float sc = g1[o] / sqrtf(v1[o] + EPSF);
        W1b[i] = f2bf(w1[i] * sc);
    }
    for (int i = gid; i < 256 * 128; i += stride) {
        const int o = i >> 7;
        const float sc = g2[o] / sqrtf(v2[o] + EPSF);
        W2b[i] = f2bf(w2[i] * sc);
    }
}

// ---------------------------------------------------------------------------
// Kernel 1: FPS — R5/R11/R13-verbatim (measured best: 455us, VGPR 88).
// 511-step serial chain; 6 restructuring attempts (R6-R10) all failed or
// spilled -> structural floor for exact FPS on 32 CUs.
// ---------------------------------------------------------------------------
__global__ __launch_bounds__(512) void fps_kernel(const float* __restrict__ pts,
                                                  float* __restrict__ centers) {
    __shared__ float4 sxyz[N_];  // 128KB
    __shared__ __align__(16) unsigned long long rowkeys[2][32];

    const int b = blockIdx.x;
    const int t = threadIdx.x;
    const int l = t & 63;
    const int w = t >> 6;
    const float* p = pts + (size_t)b * (N_ * 3);

    float px[16], py[16], pz[16], md[16];
#pragma unroll
    for (int j = 0; j < 16; ++j) {
        const int idx = t + j * 512;
        px[j] = p[3 * idx + 0];
        py[j] = p[3 * idx + 1];
        pz[j] = p[3 * idx + 2];
        sxyz[idx] = make_float4(px[j], py[j], pz[j], 0.0f);
        md[j] = 1e10f;
    }
    __syncthreads();

    if (t == 0) {
        float* c = centers + (size_t)b * (G_ * 3);
        c[0] = px[0]; c[1] = py[0]; c[2] = pz[0];
    }
    const float4 c0 = sxyz[0];
    float lx = c0.x, ly = c0.y, lz = c0.z;
    const int pay0 = 8191 - t;  // idx = t + j*512 -> pay = pay0 - (j<<9)

    for (int g = 1; g < G_; ++g) {
        float m_best = -1.0f;
        int j_best = 0;
#pragma unroll
        for (int j = 0; j < 16; ++j) {
            const float dx = __fsub_rn(px[j], lx);
            const float dy = __fsub_rn(py[j], ly);
            const float dz = __fsub_rn(pz[j], lz);
            const float d = __fadd_rn(__fadd_rn(__fmul_rn(dx, dx), __fmul_rn(dy, dy)),
                                      __fmul_rn(dz, dz));
            const float m = fminf(md[j], d);
            md[j] = m;
            const bool c = m > m_best;  // strict: keeps smallest j on ties
            m_best = c ? m : m_best;
            j_best = c ? j : j_best;
        }
        unsigned long long key =
            ((unsigned long long)__float_as_uint(m_best) << 13) |
            (unsigned long long)(unsigned)(pay0 - (j_best << 9));

        key = u64max(key, dpp_shr_u64<0x111>(key));
        key = u64max(key, dpp_shr_u64<0x112>(key));
        key = u64max(key, dpp_shr_u64<0x114>(key));
        key = u64max(key, dpp_shr_u64<0x118>(key));
        if ((l & 15) == 15) rowkeys[g & 1][w * 4 + (l >> 4)] = key;  // 32 rows
        __syncthreads();

        const u64x2* rk = (const u64x2*)&rowkeys[g & 1][0];
        const u64x2 k2 = rk[l & 15];
        unsigned long long kk = u64max(k2[0], k2[1]);
        kk = u64max(kk, dpp_shr_u64<0x111>(kk));
        kk = u64max(kk, dpp_shr_u64<0x112>(kk));
        kk = u64max(kk, dpp_shr_u64<0x114>(kk));
        kk = u64max(kk, dpp_shr_u64<0x118>(kk));
        const unsigned blo =
            (unsigned)__builtin_amdgcn_readlane((int)(unsigned)kk, 15);
        const int last = 8191 - (int)(blo & 0x1FFFu);

        const float4 cc = sxyz[last];  // broadcast read
        lx = cc.x; ly = cc.y; lz = cc.z;
        if (t == 0) {
            float* c = centers + ((size_t)b * G_ + g) * 3;
            c[0] = lx; c[1] = ly; c[2] = lz;
        }
    }
}

// ---------------------------------------------------------------------------
// Kernel 2: kNN v3.1 — R13-verbatim (measured best: knn ~335us, total 881).
// u32 dist ladder -> m*; ballot-gated idx resolution (fast readlane path /
// exact idx-min ladder on multi-tie); owner-only u64 rescan; rank-merge.
// ---------------------------------------------------------------------------
__global__ __launch_bounds__(256) void knn_kernel(const float* __restrict__ pts,
                                                  const float* __restrict__ centers,
                                                  float* __restrict__ neigh) {
    __shared__ unsigned long long wkeys[4][32];
    __shared__ int midx[32];

    const int cid = blockIdx.x;
    const int b = cid >> 9;
    const int t = threadIdx.x;
    const int w = t >> 6;
    const int l = t & 63;
    const float* p = pts + (size_t)b * (N_ * 3);
    const float* c = centers + (size_t)cid * 3;
    const float cx = c[0], cy = c[1], cz = c[2];

    const int iy0 = (w << 11) + l;

    unsigned int db[32];
#pragma unroll
    for (int i = 0; i < 32; ++i) {
        const int idx = iy0 + (i << 6);
        const float dx = __fsub_rn(p[3 * idx + 0], cx);
        const float dy = __fsub_rn(p[3 * idx + 1], cy);
        const float dz = __fsub_rn(p[3 * idx + 2], cz);
        const float d = __fadd_rn(__fadd_rn(__fmul_rn(dx, dx), __fmul_rn(dy, dy)),
                                  __fmul_rn(dz, dz));
        db[i] = __float_as_uint(d);
    }

    unsigned int excl = 0u;
    unsigned long long gm0, gm1, gm2, gm3;

#define KNN_SCAN_GROUP(G, DEST)                                               \
    {                                                                         \
        unsigned long long nm = ~0ull;                                        \
        _Pragma("unroll") for (int j = 0; j < 8; ++j) {                       \
            const int i = ((G) << 3) + j;                                     \
            if (!(excl & (1u << i))) {                                        \
                const unsigned long long k2 =                                 \
                    ((unsigned long long)db[i] << 13) |                       \
                    (unsigned long long)(unsigned)(iy0 + (i << 6));           \
                nm = (nm < k2) ? nm : k2;                                     \
            }                                                                 \
        }                                                                     \
        DEST = nm;                                                            \
    }

    KNN_SCAN_GROUP(0, gm0)
    KNN_SCAN_GROUP(1, gm1)
    KNN_SCAN_GROUP(2, gm2)
    KNN_SCAN_GROUP(3, gm3)
    unsigned long long lkey = u64min(u64min(gm0, gm1), u64min(gm2, gm3));

    for (int r = 0; r < K_; ++r) {
        // ladder 1: min distance bits (32-bit)
        const unsigned vd = (unsigned)(lkey >> 13);
        const unsigned mstar = wave_min_u32(vd);

        // winner index: ballot-gated
        const unsigned long long bal = __ballot(vd == mstar);
        unsigned istar;
        if (__popcll(bal) == 1) {
            // unique dist-winner lane: pull its idx with one readlane
            const int wl = (int)(__ffsll((long long)bal) - 1);
            istar = (unsigned)__builtin_amdgcn_readlane(
                (int)(unsigned)(lkey & 0x1FFFull), wl);
        } else {
            // rare multi-tie: exact idx-min ladder among tied lanes
            unsigned il = (vd == mstar) ? (unsigned)(lkey & 0x1FFFull) : 0xFFFFFFFFu;
            il = umin32(il, dpp_upd_u32<0x111>(il));
            il = umin32(il, dpp_upd_u32<0x112>(il));
            il = umin32(il, dpp_upd_u32<0x114>(il));
            il = umin32(il, dpp_upd_u32<0x118>(il));
            il = umin32(il, dpp_upd_u32<0x142>(il));
            il = umin32(il, dpp_upd_u32<0x143>(il));
            istar = (unsigned)__builtin_amdgcn_readlane((int)il, 63);
        }

        const unsigned long long best =
            ((unsigned long long)mstar << 13) | (unsigned long long)istar;

        if (best == lkey) {  // unique owner (idx unique)
            const int i = ((int)istar >> 6) & 31;
            excl |= 1u << i;
            switch (i >> 3) {
                case 0: KNN_SCAN_GROUP(0, gm0) break;
                case 1: KNN_SCAN_GROUP(1, gm1) break;
                case 2: KNN_SCAN_GROUP(2, gm2) break;
                default: KNN_SCAN_GROUP(3, gm3) break;
            }
            lkey = u64min(u64min(gm0, gm1), u64min(gm2, gm3));
        }
        if (l == 0) wkeys[w][r] = best;
    }
#undef KNN_SCAN_GROUP
    __syncthreads();

    // parallel rank-merge of 4 sorted 32-lists (keys unique -> strict less)
    if (t < 128) {
        const int wv = t >> 5;
        const int pos = t & 31;
        const unsigned long long mykey = wkeys[wv][pos];
        int rank = pos;
#pragma unroll
        for (int d = 1; d < 4; ++d) {
            const int ol = (wv + d) & 3;
            int cnt = 0;
#pragma unroll
            for (int s = 32; s >= 1; s >>= 1) {
                const int n = cnt + s;
                if (n <= 32 && wkeys[ol][n - 1] < mykey) cnt = n;
            }
            rank += cnt;
        }
        if (rank < 32) midx[rank] = (int)(mykey & 0x1FFFull);
    }
    __syncthreads();

    if (t < 32) {
        const int idx = midx[t];
        float* o3 = neigh + (((size_t)cid * K_) + t) * 3;
        o3[0] = __fsub_rn(p[3 * idx + 0], cx);
        o3[1] = __fsub_rn(p[3 * idx + 1], cy);
        o3[2] = __fsub_rn(p[3 * idx + 2], cz);
    }
}

// ---------------------------------------------------------------------------
// Kernel 3: MFMA MLP (unchanged from R4-R14 — proven). 512 thr x 256 pts/blk.
// ---------------------------------------------------------------------------
__global__ __launch_bounds__(512) void mlp_kernel(
    const float* __restrict__ neigh, const float* __restrict__ W0b,
    const float* __restrict__ b1b, const float* __restrict__ b2b,
    const short* __restrict__ W1b, const short* __restrict__ W2b,
    float* __restrict__ out) {
    __shared__ bf16x8 lw1v[1024];
    __shared__ bf16x8 lw2v[4096];
    __shared__ bf16x8 lh2v[8 * 512];
    __shared__ float lw0[256];
    __shared__ float lb1[128];
    __shared__ float lb2[256];
    __shared__ float colmax[256];

    const int t = threadIdx.x;
    const int w = t >> 6;
    const int l = t & 63;
    const int lr = l & 15;
    const int lg = l >> 4;

    {
        char* d1 = (char*)lw1v;
        for (int i = t; i < 1024; i += 512) {
            const int d = i * 16;
            const int src = d ^ ((((unsigned)d >> 7) & 7) << 4);
            *(bf16x8*)(d1 + d) = *(const bf16x8*)((const char*)W1b + src);
        }
        char* d2 = (char*)lw2v;
        for (int i = t; i < 4096; i += 512) {
            const int d = i * 16;
            const int src = d ^ ((((unsigned)d >> 8) & 7) << 4);
            *(bf16x8*)(d2 + d) = *(const bf16x8*)((const char*)W2b + src);
        }
        if (t < 256) lw0[t] = W0b[t];
        if (t < 128) lb1[t] = b1b[t];
        if (t < 256) lb2[t] = b2b[t];
        if (t < 256) colmax[t] = 0.0f;
    }
    __syncthreads();

    const size_t pbase = (size_t)blockIdx.x * 256 + w * 32;
    bf16x8 a1[2][2];
#pragma unroll
    for (int m = 0; m < 2; ++m) {
        const float* pp = neigh + (pbase + m * 16 + lr) * 3;
        const float x0 = pp[0], x1 = pp[1], x2 = pp[2];
#pragma unroll
        for (int s = 0; s < 2; ++s) {
            bf16x8 v;
#pragma unroll
            for (int j = 0; j < 8; ++j) {
                const int c = s * 32 + lg * 8 + j;
                const float4 wv = *(const float4*)&lw0[c * 4];
                float val = fmaf(x2, wv.z, fmaf(x1, wv.y, x0 * wv.x)) + wv.w;
                v[j] = f2bf(fmaxf(val, 0.0f));
            }
            a1[m][s] = v;
        }
    }

    const f32x4 vzero = {0.f, 0.f, 0.f, 0.f};
    f32x4 acc2[2][8];
#pragma unroll
    for (int m = 0; m < 2; ++m)
#pragma unroll
        for (int n = 0; n < 8; ++n) acc2[m][n] = vzero;

    const char* w1p = (const char*)lw1v;
#pragma unroll
    for (int s = 0; s < 2; ++s) {
#pragma unroll
        for (int n = 0; n < 8; ++n) {
            const int o = n * 16 + lr;
            int byte = o * 128 + s * 64 + lg * 16;
            byte ^= ((o & 7) << 4);
            const bf16x8 bfr = *(const bf16x8*)(w1p + byte);
            acc2[0][n] = __builtin_amdgcn_mfma_f32_16x16x32_bf16(a1[0][s], bfr, acc2[0][n], 0, 0, 0);
            acc2[1][n] = __builtin_amdgcn_mfma_f32_16x16x32_bf16(a1[1][s], bfr, acc2[1][n], 0, 0, 0);
        }
    }

    char* myh2 = (char*)(lh2v + w * 512);
#pragma unroll
    for (int m = 0; m < 2; ++m)
#pragma unroll
        for (int n = 0; n < 8; ++n) {
            const int o = n * 16 + lr;
            const float bb = lb1[o];
#pragma unroll
            for (int q = 0; q < 4; ++q) {
                const int row = m * 16 + lg * 4 + q;
                int byte = row * 256 + o * 2;
                byte ^= ((row & 7) << 4);
                *(short*)(myh2 + byte) = f2bf(fmaxf(acc2[m][n][q] + bb, 0.0f));
            }
        }

    f32x4 acc3[2][16];
#pragma unroll
    for (int m = 0; m < 2; ++m)
#pragma unroll
        for (int n = 0; n < 16; ++n) acc3[m][n] = vzero;

    const char* w2p = (const char*)lw2v;
#pragma unroll
    for (int s = 0; s < 4; ++s) {
        bf16x8 a[2];
#pragma unroll
        for (int m = 0; m < 2; ++m) {
            const int row = m * 16 + lr;
            int byte = row * 256 + s * 64 + lg * 16;
            byte ^= ((row & 7) << 4);
            a[m] = *(const bf16x8*)(myh2 + byte);
        }
#pragma unroll
        for (int n = 0; n < 16; ++n) {
            const int o = n * 16 + lr;
            int byte = o * 256 + s * 64 + lg * 16;
            byte ^= ((o & 7) << 4);
            const bf16x8 bfr = *(const bf16x8*)(w2p + byte);
            acc3[0][n] = __builtin_amdgcn_mfma_f32_16x16x32_bf16(a[0], bfr, acc3[0][n], 0, 0, 0);
            acc3[1][n] = __builtin_amdgcn_mfma_f32_16x16x32_bf16(a[1], bfr, acc3[1][n], 0, 0, 0);
        }
    }

#pragma unroll
    for (int n = 0; n < 16; ++n) {
        const int o = n * 16 + lr;
        const float bb = lb2[o];
        float mx = 0.0f;
#pragma unroll
        for (int m = 0; m < 2; ++m)
#pragma unroll
            for (int q = 0; q < 4; ++q) mx = fmaxf(mx, acc3[m][n][q] + bb);
        mx = fmaxf(mx, 0.0f);
        mx = fmaxf(mx, __shfl_xor(mx, 16, 64));
        mx = fmaxf(mx, __shfl_xor(mx, 32, 64));
        if (lg == 0) atomicMax((unsigned int*)&colmax[o], __float_as_uint(mx));
    }
    __syncthreads();
    if (t < 256) {
        const int b = (int)(blockIdx.x >> 6);
        atomicMax((unsigned int*)out + b * 256 + t, __float_as_uint(colmax[t]));
    }
}

// ---------------------------------------------------------------------------
extern "C" void kernel_launch(void* const* d_in, const int* in_sizes, int n_in,
                              void* d_out, int out_size, void* d_ws, size_t ws_size,
                              hipStream_t stream) {
    const float* pts = (const float*)d_in[0];
    const float* w0 = (const float*)d_in[1];
    const float* b0 = (const float*)d_in[2];
    const float* g0 = (const float*)d_in[3];
    const float* be0 = (const float*)d_in[4];
    const float* m0 = (const float*)d_in[5];
    const float* v0 = (const float*)d_in[6];
    const float* w1 = (const float*)d_in[7];
    const float* b1 = (const float*)d_in[8];
    const float* g1 = (const float*)d_in[9];
    const float* be1 = (const float*)d_in[10];
    const float* m1 = (const float*)d_in[11];
    const float* v1 = (const float*)d_in[12];
    const float* w2 = (const float*)d_in[13];
    const float* b2 = (const float*)d_in[14];
    const float* g2 = (const float*)d_in[15];
    const float* be2 = (const float*)d_in[16];
    const float* m2 = (const float*)d_in[17];
    const float* v2 = (const float*)d_in[18];

    char* ws = (char*)d_ws;
    float* centers = (float*)ws;                        // 192KB @ 0
    float* neigh = (float*)(ws + (size_t)262144);       // 6.29MB
    char* wb = ws + (size_t)6553600;                    // weights region
    float* W0b = (float*)(wb + 0);                      // 1KB
    float* b1b = (float*)(wb + 1024);                   // 512B
    float* b2b = (float*)(wb + 1536);                   // 1KB
    short* W1b = (short*)(wb + 2560);                   // 16KB
    short* W2b = (short*)(wb + 2560 + 16384);           // 64KB

    hipMemsetAsync(d_out, 0, (size_t)out_size * sizeof(float), stream);
    prep_kernel<<<17, 256, 0, stream>>>(w0, b0, g0, be0, m0, v0,
                                        w1, b1, g1, be1, m1, v1,
                                        w2, b2, g2, be2, m2, v2,
                                        W0b, b1b, b2b, W1b, W2b);
    fps_kernel<<<B_, 512, 0, stream>>>(pts, centers);
    knn_kernel<<<B_ * G_, 256, 0, stream>>>(pts, centers, neigh);
    mlp_kernel<<<(B_ * G_ * K_) / 256, 512, 0, stream>>>(
        neigh, W0b, b1b, b2b, W1b, W2b, (float*)d_out);
}